// Round 21
// baseline (6186.932 us; speedup 1.0000x reference)
//
#include <hip/hip_runtime.h>

#define T_STEPS 1024
#define BSZ 256
#define HD 256
#define OUTC 64
#define NT 32           // steps per phase
#define NPHASE 32
#define TBB 8           // steps per subgroup in kernB/kernD
#define BT 16           // steps per kernB/kernD block (2 subgroups)

// ---------------- ws layout (float offsets), total ~35.7 MB ----------------
static const size_t OFF_SUM  = 0;                      // [256][256]
static const size_t OFF_FLAG = 65536;                  // int flag
static const size_t OFF_WP   = 65600;                  // 3 x [128][256] float4
static const size_t OFF_CEH  = 458816;                 // [NT][256][256]
static const size_t OFF_CEO  = 2555968;                // [NT][256][256]
static const size_t OFF_H    = 4653120;                // [NT+1][256][256]
static const size_t OFF_A2   = 6815808;                // [NT][256][256]

// x-dtype detector: if x is int64, all sampled high 32-bit words are zero.
__global__ void detect_x(const int* __restrict__ x, float* __restrict__ ws) {
    __shared__ int nonzero;
    if (threadIdx.x == 0) nonzero = 0;
    __syncthreads();
    if (x[2 * threadIdx.x + 1] != 0) nonzero = 1;   // benign same-value race
    __syncthreads();
    if (threadIdx.x == 0) *(int*)(ws + OFF_FLAG) = (nonzero == 0) ? 1 : 0;
}

// Pack weights as float4 per (k-quad, column): Wp[z][q][j] = {W_z[j][4q+c]}.
__global__ void prep_pack(const float* __restrict__ Wi2h,
                          const float* __restrict__ Wi2o,
                          const float* __restrict__ Wo2o,
                          float* __restrict__ ws) {
    const int q = blockIdx.x;            // 0..127 (k quad)
    const int z = blockIdx.y;            // 0..2
    const int j = threadIdx.x;           // 0..255 (column)
    const float* src = (z == 0) ? Wi2h : (z == 1) ? Wi2o : Wo2o;
    const float4 v = *reinterpret_cast<const float4*>(src + (size_t)j * 512 + 4 * q);
    reinterpret_cast<float4*>(ws + OFF_WP)[((size_t)z * 128 + q) * 256 + j] = v;
}

// exact-bit wave broadcast: value of v at lane l
__device__ __forceinline__ float RLf(float v, int l) {
    return __int_as_float(__builtin_amdgcn_readlane(__float_as_int(v), l));
}

// ---- kernB: e-part chains (k=0..255) for hn and o. Block = 2 subgroups x
// 128 threads; subgroup sg handles 8 t's; thread covers columns lj, lj+128.
// Distance-1 weight prefetch: next-q weights load before current FMA block
// (hides ~250cy L2 latency under the ~256cy FMA block). Chains bit-exact.
__global__ __launch_bounds__(256) void kernB(
    const int* __restrict__ x, const float* __restrict__ emb,
    const float* __restrict__ boo, float* __restrict__ ws, int phase) {
    const int tid = threadIdx.x;
    const int sg = tid >> 7;            // subgroup 0/1
    const int lj = tid & 127;
    const int j0 = lj, j1 = lj + 128;
    const int ti = blockIdx.x;          // 0/1 (16-t tile)
    const int row = blockIdx.y;
    const int mode64 = *(const int*)(ws + OFF_FLAG);
    const float4* __restrict__ Wh4  = reinterpret_cast<const float4*>(ws + OFF_WP);
    const float4* __restrict__ Wio4 = Wh4 + (size_t)128 * 256;

    // fold previous phase's a2 into SUM (t-ascending, exact f32 chain)
    if (ti == 0 && phase > 0) {
        const size_t rb = (size_t)row * 256 + tid;
        float av[NT];
        #pragma unroll
        for (int i = 0; i < NT; ++i)
            av[i] = ws[OFF_A2 + (size_t)i * 65536 + rb];
        float s = (phase == 1) ? 0.f : ws[OFF_SUM + rb];
        const float boo_j = boo[tid];
        #pragma unroll
        for (int i = 0; i < NT; ++i) s += (av[i] + boo_j);
        ws[OFF_SUM + rb] = s;
    }

    __shared__ int toks[BT];
    __shared__ __align__(16) float eW[BT][256];
    if (tid < BT) {
        const int t = phase * NT + ti * BT + tid;
        toks[tid] = mode64 ? x[2 * (t * BSZ + row)] : x[t * BSZ + row];
    }
    __syncthreads();
    #pragma unroll
    for (int v = 0; v < BT; ++v)
        eW[v][tid] = emb[(size_t)toks[v] * HD + tid];
    __syncthreads();

    float aH[TBB][2], aO[TBB][2];
    #pragma unroll
    for (int u = 0; u < TBB; ++u) {
        aH[u][0] = 0.f; aH[u][1] = 0.f; aO[u][0] = 0.f; aO[u][1] = 0.f;
    }
    float4 whA = Wh4[j0],  whB = Wh4[j1];
    float4 woA = Wio4[j0], woB = Wio4[j1];
    #pragma unroll 2
    for (int q = 0; q < 64; ++q) {
        const int qn = (q + 1) & 63;    // wrap; q=63 prefetch unused
        const float4 nhA = Wh4[(size_t)qn * 256 + j0];
        const float4 nhB = Wh4[(size_t)qn * 256 + j1];
        const float4 noA = Wio4[(size_t)qn * 256 + j0];
        const float4 noB = Wio4[(size_t)qn * 256 + j1];
        #pragma unroll
        for (int u = 0; u < TBB; ++u) {
            const float4 e = *reinterpret_cast<const float4*>(&eW[sg * TBB + u][4 * q]);
            aH[u][0] = fmaf(e.x, whA.x, aH[u][0]); aH[u][1] = fmaf(e.x, whB.x, aH[u][1]);
            aO[u][0] = fmaf(e.x, woA.x, aO[u][0]); aO[u][1] = fmaf(e.x, woB.x, aO[u][1]);
            aH[u][0] = fmaf(e.y, whA.y, aH[u][0]); aH[u][1] = fmaf(e.y, whB.y, aH[u][1]);
            aO[u][0] = fmaf(e.y, woA.y, aO[u][0]); aO[u][1] = fmaf(e.y, woB.y, aO[u][1]);
            aH[u][0] = fmaf(e.z, whA.z, aH[u][0]); aH[u][1] = fmaf(e.z, whB.z, aH[u][1]);
            aO[u][0] = fmaf(e.z, woA.z, aO[u][0]); aO[u][1] = fmaf(e.z, woB.z, aO[u][1]);
            aH[u][0] = fmaf(e.w, whA.w, aH[u][0]); aH[u][1] = fmaf(e.w, whB.w, aH[u][1]);
            aO[u][0] = fmaf(e.w, woA.w, aO[u][0]); aO[u][1] = fmaf(e.w, woB.w, aO[u][1]);
        }
        whA = nhA; whB = nhB; woA = noA; woB = noB;
    }
    const size_t rb = (size_t)row * 256;
    #pragma unroll
    for (int u = 0; u < TBB; ++u) {
        const size_t off = (size_t)(ti * BT + sg * TBB + u) * 65536 + rb;
        ws[OFF_CEH + off + j0] = aH[u][0];
        ws[OFF_CEH + off + j1] = aH[u][1];
        ws[OFF_CEO + off + j0] = aO[u][0];
        ws[OFF_CEO + off + j1] = aO[u][1];
    }
}

// ---- kernC: NT sequential recurrence steps; whr[64] register-resident.
// Mixed broadcast (even quads DS, odd quads readlane) fills the serial
// accumulator-chain latency. Ping-pong h buffers -> ONE barrier per step.
__global__ __launch_bounds__(256) void kernC(
    const float* __restrict__ bih, float* __restrict__ ws, int phase) {
    const int j = threadIdx.x;
    const int lane = j & 63;
    const int row = blockIdx.x;
    const float4* __restrict__ Wh4 = reinterpret_cast<const float4*>(ws + OFF_WP);

    float4 whr[64];
    #pragma unroll
    for (int q = 0; q < 64; ++q) whr[q] = Wh4[(size_t)(64 + q) * 256 + j];

    __shared__ __align__(16) float hPing[256];
    __shared__ __align__(16) float hPong[256];
    float* __restrict__ Hp = ws + OFF_H;
    const float* __restrict__ CE = ws + OFF_CEH;
    const size_t rb = (size_t)row * 256 + j;

    const float hc = (phase == 0) ? 0.f : Hp[(size_t)NT * 65536 + rb]; // carry
    Hp[rb] = hc;                       // H[0] = h at phase start
    hPing[j] = hc;
    const float bih_j = bih[j];
    float ceCur = CE[rb];
    __syncthreads();

    #pragma unroll 1
    for (int i = 0; i < NT; ++i) {
        const float ceNext = (i + 1 < NT) ? CE[(size_t)(i + 1) * 65536 + rb] : 0.f;
        const float* __restrict__ hb = (i & 1) ? hPong : hPing;
        float* __restrict__ hnb      = (i & 1) ? hPing : hPong;
        const float4 h4 = *reinterpret_cast<const float4*>(&hb[4 * lane]);
        float ah = ceCur;
        #pragma unroll
        for (int p2 = 0; p2 < 32; ++p2) {
            const int q0 = 2 * p2, q1 = 2 * p2 + 1;
            const float4 a = *reinterpret_cast<const float4*>(&hb[4 * q0]); // DS bcast
            ah = fmaf(a.x, whr[q0].x, ah);
            ah = fmaf(a.y, whr[q0].y, ah);
            ah = fmaf(a.z, whr[q0].z, ah);
            ah = fmaf(a.w, whr[q0].w, ah);
            ah = fmaf(RLf(h4.x, q1), whr[q1].x, ah);
            ah = fmaf(RLf(h4.y, q1), whr[q1].y, ah);
            ah = fmaf(RLf(h4.z, q1), whr[q1].z, ah);
            ah = fmaf(RLf(h4.w, q1), whr[q1].w, ah);
        }
        const float hn = ah + bih_j;                   // + b_i2h
        Hp[(size_t)(i + 1) * 65536 + rb] = hn;         // publish to ws
        hnb[j] = hn;                                   // other buffer: no WAR
        ceCur = ceNext;
        __syncthreads();                               // publish for next step
    }
}

// ---- kernD: finish o (h-part) and out-chains; 2 subgroups x 128 threads,
// C=2 cols. Same-address ds_read_b128 broadcasts; distance-1 weight prefetch.
// Chains 1 (o h-part, h_t) + 2 (out hn-part, h_{t+1}) fused per q; chain 3
// (out o-part) after the oS hop. All chains bit-exact k-ascending.
__global__ __launch_bounds__(256) void kernD(
    const float* __restrict__ bio, float* __restrict__ ws, int phase) {
    const int tid = threadIdx.x;
    const int sg = tid >> 7;
    const int lj = tid & 127;
    const int j0 = lj, j1 = lj + 128;
    const int ti = blockIdx.x;          // 0/1
    const int row = blockIdx.y;
    const float4* __restrict__ Wh4  = reinterpret_cast<const float4*>(ws + OFF_WP);
    const float4* __restrict__ Wio4 = Wh4 + (size_t)128 * 256;
    const float4* __restrict__ Woo4 = Wh4 + (size_t)256 * 256;

    __shared__ __align__(16) float hS[BT + 1][256];   // 17 KB
    __shared__ __align__(16) float oS[BT][256];       // 16 KB
    const float* __restrict__ Hp = ws + OFF_H;
    const size_t rb = (size_t)row * 256;

    #pragma unroll
    for (int v = 0; v <= BT; ++v)
        hS[v][tid] = Hp[(size_t)(ti * BT + v) * 65536 + rb + tid];
    float co[TBB][2], a2[TBB][2];
    #pragma unroll
    for (int u = 0; u < TBB; ++u) {
        const size_t off = OFF_CEO + (size_t)(ti * BT + sg * TBB + u) * 65536 + rb;
        co[u][0] = ws[off + j0];
        co[u][1] = ws[off + j1];
        a2[u][0] = 0.f; a2[u][1] = 0.f;
    }
    __syncthreads();

    // fused chains 1+2 with distance-1 weight prefetch
    float4 w1A = Wio4[(size_t)64 * 256 + j0];
    float4 w1B = Wio4[(size_t)64 * 256 + j1];
    float4 w2A = Woo4[j0];
    float4 w2B = Woo4[j1];
    #pragma unroll 2
    for (int q = 0; q < 64; ++q) {
        const int qn = (q + 1) & 63;
        const float4 n1A = Wio4[(size_t)(64 + qn) * 256 + j0];
        const float4 n1B = Wio4[(size_t)(64 + qn) * 256 + j1];
        const float4 n2A = Woo4[(size_t)qn * 256 + j0];
        const float4 n2B = Woo4[(size_t)qn * 256 + j1];
        float4 hq[TBB + 1];
        #pragma unroll
        for (int v = 0; v <= TBB; ++v)
            hq[v] = *reinterpret_cast<const float4*>(&hS[sg * TBB + v][4 * q]);
        #pragma unroll
        for (int u = 0; u < TBB; ++u) {
            co[u][0] = fmaf(hq[u].x, w1A.x, co[u][0]);
            co[u][1] = fmaf(hq[u].x, w1B.x, co[u][1]);
            co[u][0] = fmaf(hq[u].y, w1A.y, co[u][0]);
            co[u][1] = fmaf(hq[u].y, w1B.y, co[u][1]);
            co[u][0] = fmaf(hq[u].z, w1A.z, co[u][0]);
            co[u][1] = fmaf(hq[u].z, w1B.z, co[u][1]);
            co[u][0] = fmaf(hq[u].w, w1A.w, co[u][0]);
            co[u][1] = fmaf(hq[u].w, w1B.w, co[u][1]);
            a2[u][0] = fmaf(hq[u + 1].x, w2A.x, a2[u][0]);
            a2[u][1] = fmaf(hq[u + 1].x, w2B.x, a2[u][1]);
            a2[u][0] = fmaf(hq[u + 1].y, w2A.y, a2[u][0]);
            a2[u][1] = fmaf(hq[u + 1].y, w2B.y, a2[u][1]);
            a2[u][0] = fmaf(hq[u + 1].z, w2A.z, a2[u][0]);
            a2[u][1] = fmaf(hq[u + 1].z, w2B.z, a2[u][1]);
            a2[u][0] = fmaf(hq[u + 1].w, w2A.w, a2[u][0]);
            a2[u][1] = fmaf(hq[u + 1].w, w2B.w, a2[u][1]);
        }
        w1A = n1A; w1B = n1B; w2A = n2A; w2B = n2B;
    }
    const float bio_j0 = bio[j0], bio_j1 = bio[j1];
    #pragma unroll
    for (int u = 0; u < TBB; ++u) {
        oS[sg * TBB + u][j0] = co[u][0] + bio_j0;     // + b_i2o
        oS[sg * TBB + u][j1] = co[u][1] + bio_j1;
    }
    __syncthreads();

    // chain 3: out o-part (k = 256..511), weight prefetch distance 1
    float4 w3A = Woo4[(size_t)64 * 256 + j0];
    float4 w3B = Woo4[(size_t)64 * 256 + j1];
    #pragma unroll 2
    for (int q = 0; q < 64; ++q) {
        const int qn = (q + 1) & 63;
        const float4 n3A = Woo4[(size_t)(64 + qn) * 256 + j0];
        const float4 n3B = Woo4[(size_t)(64 + qn) * 256 + j1];
        #pragma unroll
        for (int u = 0; u < TBB; ++u) {
            const float4 o4 = *reinterpret_cast<const float4*>(&oS[sg * TBB + u][4 * q]);
            a2[u][0] = fmaf(o4.x, w3A.x, a2[u][0]);
            a2[u][1] = fmaf(o4.x, w3B.x, a2[u][1]);
            a2[u][0] = fmaf(o4.y, w3A.y, a2[u][0]);
            a2[u][1] = fmaf(o4.y, w3B.y, a2[u][1]);
            a2[u][0] = fmaf(o4.z, w3A.z, a2[u][0]);
            a2[u][1] = fmaf(o4.z, w3B.z, a2[u][1]);
            a2[u][0] = fmaf(o4.w, w3A.w, a2[u][0]);
            a2[u][1] = fmaf(o4.w, w3B.w, a2[u][1]);
        }
        w3A = n3A; w3B = n3B;
    }
    #pragma unroll
    for (int u = 0; u < TBB; ++u) {
        const size_t off = OFF_A2 + (size_t)(ti * BT + sg * TBB + u) * 65536 + rb;
        ws[off + j0] = a2[u][0];
        ws[off + j1] = a2[u][1];
    }
}

// encoded: fold LAST phase's a2 (t-ascending, exact), /1024; logits; softmax;
// first-index argmax over f32 lp.
__global__ __launch_bounds__(64) void final_k(
    const float* __restrict__ Wpred, const float* __restrict__ bpred,
    const float* __restrict__ boo, const float* __restrict__ ws,
    float* __restrict__ out) {
    const int b = blockIdx.x, o = threadIdx.x;
    __shared__ float enc[256];
    __shared__ float exs[64];
    __shared__ float s32s;

    #pragma unroll
    for (int u = 0; u < 4; ++u) {
        const int j = o * 4 + u;
        const size_t rb = (size_t)b * 256 + j;
        float av[NT];
        #pragma unroll
        for (int i = 0; i < NT; ++i)
            av[i] = ws[OFF_A2 + (size_t)i * 65536 + rb];
        float s = ws[OFF_SUM + rb];
        const float boo_j = boo[j];
        #pragma unroll
        for (int i = 0; i < NT; ++i) s += (av[i] + boo_j);
        enc[j] = s * (1.0f / 1024.0f);
    }
    __syncthreads();

    float acc = 0.f;
    for (int e = 0; e < 256; ++e)
        acc = fmaf(enc[e], Wpred[(size_t)o * 256 + e], acc);
    acc += bpred[o];                      // logits[b][o], f32

    float m = acc;
    #pragma unroll
    for (int d = 1; d < 64; d <<= 1) m = fmaxf(m, __shfl_xor(m, d));
    const float sh = acc - m;
    const float ex = (float)exp((double)sh);
    exs[o] = ex;
    __syncthreads();
    if (o == 0) {
        double sd = 0.0;
        for (int i = 0; i < 64; ++i) sd += (double)exs[i];
        s32s = (float)sd;
    }
    __syncthreads();
    const float log_s = (float)log((double)s32s);
    const float lp = sh - log_s;
    const float pr = (float)exp((double)lp);

    float av = lp; int ai = o;
    #pragma unroll
    for (int d = 1; d < 64; d <<= 1) {
        const float ov = __shfl_xor(av, d);
        const int oi = __shfl_xor(ai, d);
        if (ov > av || (ov == av && oi < ai)) { av = ov; ai = oi; }
    }

    out[BSZ + (size_t)b * OUTC + o] = lp;              // logprobs
    out[BSZ + 16384 + (size_t)b * OUTC + o] = pr;      // probs
    if (o == 0) out[b] = (float)ai;                    // preds
}

// ---------------- host ----------------
extern "C" void kernel_launch(void* const* d_in, const int* in_sizes, int n_in,
                              void* d_out, int out_size, void* d_ws, size_t ws_size,
                              hipStream_t stream) {
    const int*   x     = (const int*)d_in[0];
    const float* emb   = (const float*)d_in[1];
    const float* Wi2h  = (const float*)d_in[2];
    const float* b_ih  = (const float*)d_in[3];
    const float* Wi2o  = (const float*)d_in[4];
    const float* b_io  = (const float*)d_in[5];
    const float* Wo2o  = (const float*)d_in[6];
    const float* b_oo  = (const float*)d_in[7];
    const float* Wpred = (const float*)d_in[8];
    const float* b_p   = (const float*)d_in[9];
    float* ws  = (float*)d_ws;
    float* out = (float*)d_out;

    detect_x<<<1, 256, 0, stream>>>(x, ws);
    prep_pack<<<dim3(128, 3), 256, 0, stream>>>(Wi2h, Wi2o, Wo2o, ws);

    for (int p = 0; p < NPHASE; ++p) {
        kernB<<<dim3(2, 256), 256, 0, stream>>>(x, emb, b_oo, ws, p);
        kernC<<<dim3(256), 256, 0, stream>>>(b_ih, ws, p);
        kernD<<<dim3(2, 256), 256, 0, stream>>>(b_io, ws, p);
    }
    final_k<<<dim3(256), 64, 0, stream>>>(Wpred, b_p, b_oo, ws, out);
}